// Round 15
// baseline (128.163 us; speedup 1.0000x reference)
//
#include <hip/hip_runtime.h>
#include <hip/hip_bf16.h>
#include <stdint.h>

#define DEVI __device__ __forceinline__

using bf16 = __hip_bfloat16;
typedef __bf16 bf16x8 __attribute__((ext_vector_type(8)));
typedef __bf16 bf16x4 __attribute__((ext_vector_type(4)));
typedef float f32x4 __attribute__((ext_vector_type(4)));

static constexpr int Bb = 2, Nn = 2048, Cc = 1024, Hh = 16, Dd = 64;
static constexpr float CSC = 0.125f * 1.44269504088896340736f;  // scale*log2(e)

DEVI bf16 f2bf(float x) { __bf16 h = (__bf16)x; return *(bf16*)&h; }
DEVI float fexp2(float x) { return __builtin_amdgcn_exp2f(x); }

DEVI bf16x8 cvt8(f32x4 a, f32x4 b) {
  bf16x8 r;
  r[0] = (__bf16)a[0]; r[1] = (__bf16)a[1]; r[2] = (__bf16)a[2]; r[3] = (__bf16)a[3];
  r[4] = (__bf16)b[0]; r[5] = (__bf16)b[1]; r[6] = (__bf16)b[2]; r[7] = (__bf16)b[3];
  return r;
}

// async global->LDS, 16B/lane; LDS dest = wave-uniform base + lane*16
DEVI void gld_lds16(const bf16* g, bf16* l) {
  __builtin_amdgcn_global_load_lds(
      (__attribute__((address_space(1))) void*)(g),
      (__attribute__((address_space(3))) void*)(l),
      16, 0, 0);
}

// ---------------------------------------------------------------------------
// f32 -> bf16 pre-convert: x(2048 blks) + wq/wk/wv/wp(512 blks each) = 4096.
// ---------------------------------------------------------------------------
__global__ __launch_bounds__(256) void k_cvt(const float* __restrict__ x,
                                             const float* __restrict__ wq,
                                             const float* __restrict__ wk,
                                             const float* __restrict__ wv,
                                             const float* __restrict__ wp,
                                             bf16* xb, bf16* wqb, bf16* wkb,
                                             bf16* wvb, bf16* wpb) {
  int bid = blockIdx.x;
  const float* src; bf16* dst; size_t off;
  if (bid < 2048) {
    src = x; dst = xb; off = (size_t)bid * 2048;
  } else {
    int s = (bid - 2048) >> 9, r = (bid - 2048) & 511;
    off = (size_t)r * 2048;
    src = s == 0 ? wq : s == 1 ? wk : s == 2 ? wv : wp;
    dst = s == 0 ? wqb : s == 1 ? wkb : s == 2 ? wvb : wpb;
  }
  size_t i = off + (size_t)threadIdx.x * 8;
  f32x4 a = *(const f32x4*)(src + i);
  f32x4 b = *(const f32x4*)(src + i + 4);
  *(bf16x8*)(dst + i) = cvt8(a, b);
}

// ---------------------------------------------------------------------------
// bf16 GEMM, global_load_lds staging, m97 2-barrier structure (r8-proven).
// out[m][n] = sum_k A[m][k]*B[n][k]; BM=MFC*32, BN=128, BK=32; 256 thr.
// ---------------------------------------------------------------------------
template <int MFC, class Epi>
DEVI void gemm_lds_body(const bf16* __restrict__ A, const bf16* __restrict__ Bw,
                        int K, int m0, int n0, bf16* lA, bf16* lB, Epi epi) {
  constexpr int BM = MFC * 32;
  constexpr int PA = BM / 64;          // A 16B-chunks per thread
  const int t = threadIdx.x;
  const int lane = t & 63, wave = t >> 6;
  const int wr = wave >> 1, wc = wave & 1;

  f32x4 acc[MFC][4] = {};

  for (int k0 = 0; k0 < K; k0 += 32) {
    __syncthreads();                   // prev compute done, LDS free
#pragma unroll
    for (int p = 0; p < PA; ++p) {
      int c = p * 256 + t;
      int row = c >> 2, col = (c & 3) * 8;
      gld_lds16(A + (size_t)(m0 + row) * K + k0 + col,
                lA + (size_t)(p * 256 + wave * 64) * 8);
    }
#pragma unroll
    for (int p = 0; p < 2; ++p) {
      int c = p * 256 + t;
      int row = c >> 2, col = (c & 3) * 8;
      gld_lds16(Bw + (size_t)(n0 + row) * K + k0 + col,
                lB + (size_t)(p * 256 + wave * 64) * 8);
    }
    __syncthreads();                   // drains vmcnt -> tile ready

    bf16x8 aF[MFC];
#pragma unroll
    for (int mf = 0; mf < MFC; ++mf)
      aF[mf] = *(const bf16x8*)(lA + (wr * (BM / 2) + mf * 16 + (lane & 15)) * 32 + (lane >> 4) * 8);
#pragma unroll
    for (int nf = 0; nf < 4; ++nf) {
      bf16x8 bF = *(const bf16x8*)(lB + (wc * 64 + nf * 16 + (lane & 15)) * 32 + (lane >> 4) * 8);
#pragma unroll
      for (int mf = 0; mf < MFC; ++mf)
        acc[mf][nf] = __builtin_amdgcn_mfma_f32_16x16x32_bf16(aF[mf], bF, acc[mf][nf], 0, 0, 0);
    }
  }

#pragma unroll
  for (int mf = 0; mf < MFC; ++mf)
#pragma unroll
    for (int nf = 0; nf < 4; ++nf)
#pragma unroll
      for (int r = 0; r < 4; ++r) {
        int gm = m0 + wr * (BM / 2) + mf * 16 + (lane >> 4) * 4 + r;
        int gn = n0 + wc * 64 + nf * 16 + (lane & 15);
        epi(gm, gn, acc[mf][nf][r]);
      }
}

// Epilogues -----------------------------------------------------------------
struct EpiRope {  // rows=(b,n), cols=(h,d); RoPE (+opt scale) -> bf16 (b,h,n,d)
  bf16* dst; const float* cosw; const float* sinw; float scale;
  DEVI void operator()(int gm, int gn, float v) const {
    int b = gm >> 11, n = gm & 2047;
    int h = gn >> 6, d = gn & 63;
    int i = d >> 1;
    float c = cosw[n * 32 + i], s = sinw[n * 32 + i];
    float p = __shfl_xor(v, 1);
    float o = (d & 1) ? (p * s + v * c) : (v * c - p * s);
    dst[((size_t)(b * Hh + h) * Nn + n) * 64 + d] = f2bf(o * scale);
  }
};

struct EpiVt {  // rows=c=(h,d), cols=(b,n); -> bf16 (b,h,d,n)
  bf16* dst;
  DEVI void operator()(int gm, int gn, float v) const {
    int h = gm >> 6, d = gm & 63;
    int b = gn >> 11, n = gn & 2047;
    dst[((size_t)(b * Hh + h) * 64 + d) * Nn + n] = f2bf(v);
  }
};

struct EpiProj {  // rows=(b,n), cols=c; +bias -> f32 row-major
  float* dst; const float* bias;
  DEVI void operator()(int gm, int gn, float v) const {
    dst[(size_t)gm * Cc + gn] = v + bias[gn];
  }
};

// Fused QKV: 768 blocks, XCD-clustered by x-panel: bid%8 == x_panel%8, so all
// consumers of one 128-row x panel (q,k GEMM rows; vt GEMM cols) share an L2.
__global__ __launch_bounds__(256) void k_qkv(const bf16* __restrict__ xb,
                                             const bf16* __restrict__ wqb,
                                             const bf16* __restrict__ wkb,
                                             const bf16* __restrict__ wvb,
                                             bf16* q_ws, bf16* k_ws, bf16* vt_ws,
                                             const float* __restrict__ cw,
                                             const float* __restrict__ sw) {
  __shared__ __align__(16) bf16 smem[256 * 32];
  bf16* lA = smem;
  bf16* lB = smem + 128 * 32;
  int bid = blockIdx.x;
  if (bid < 512) {
    int sub = bid & 255;
    int c = sub & 7, rest = sub >> 3;
    int m0 = (c + 8 * (rest & 3)) * 128;   // x panel (m%8 == bid%8)
    int n0 = (rest >> 2) * 128;
    bool isq = bid < 256;
    gemm_lds_body<4>(xb, isq ? wqb : wkb, Cc, m0, n0, lA, lB,
                     EpiRope{isq ? q_ws : k_ws, cw, sw, isq ? CSC : 1.0f});
  } else {
    int sub = bid - 512;
    int c = sub & 7, rest = sub >> 3;
    int n0 = (c + 8 * (rest & 3)) * 128;   // x panel (n%8 == bid%8)
    int m0 = (rest >> 2) * 128;            // wv rows
    gemm_lds_body<4>(wvb, xb, Cc, m0, n0, lA, lB, EpiVt{vt_ws});
  }
}

// Proj: BM=64 -> grid (64,8); wgid%8 == m-panel%8 already (x-fastest linear).
__global__ __launch_bounds__(256) void k_proj(const bf16* __restrict__ A,
                                              const bf16* __restrict__ W,
                                              float* dst, const float* __restrict__ bias) {
  __shared__ __align__(16) bf16 smem[192 * 32];
  gemm_lds_body<2>(A, W, Cc, blockIdx.x * 64, blockIdx.y * 128,
                   smem, smem + 64 * 32, EpiProj{dst, bias});
}

// ---------------------------------------------------------------------------
// Flash (occupancy round): 1024 blocks x 256 thr; wave owns 16 q rows.
// LDS = 40 KB exactly -> 4 blocks/CU = 4 waves/SIMD (vs 2 before).
// Swapped QK^T (acc=S^T) -> P rows lane-local -> pbuf[q][k] packed b64
// writes; lane-local row sums; setprio on MFMA clusters; DMA double-buffer
// (pre-swizzled source). No max tracking (log2 domain, Q pre-scaled).
// XCD map: bid%8 = xcd; 4 bh per XCD -> K/V L2-resident.
// ---------------------------------------------------------------------------
__global__ __launch_bounds__(256) void k_flash(const bf16* __restrict__ q_ws,
                                               const bf16* __restrict__ k_ws,
                                               const bf16* __restrict__ vt_ws,
                                               bf16* __restrict__ attn_o) {
  __shared__ __align__(16) bf16 lK[2][64 * 64];
  __shared__ __align__(16) bf16 lV[2][64 * 64];
  __shared__ __align__(16) bf16 pbuf[4][16 * 64];

  const int t = threadIdx.x, lane = t & 63, wave = t >> 6;
  const int g = lane >> 4;
  const int bid = blockIdx.x;
  const int slot = bid >> 3;                    // [0,128) per XCD class
  const int bh = (bid & 7) * 4 + (slot >> 5);   // 4 bh per XCD
  const int q0 = (slot & 31) * 64 + wave * 16;  // 64 q-rows per block
  const bf16* qg = q_ws + (size_t)bh * Nn * 64;
  const bf16* kg = k_ws + (size_t)bh * Nn * 64;
  const bf16* vg = vt_ws + (size_t)bh * 64 * Nn;

  bf16x8 qF[2];
#pragma unroll
  for (int kd = 0; kd < 2; ++kd)
    qF[kd] = *(const bf16x8*)(qg + (size_t)(q0 + (lane & 15)) * 64 + kd * 32 + g * 8);

  f32x4 accO[4] = {};
  float LsL = 0.f;                     // per-lane partial sum (q = lane&15)

  auto stage_tile = [&](int kt, int buf) {
#pragma unroll
    for (int p = 0; p < 2; ++p) {
      int c = p * 256 + t;             // 64 rows x 8 chunks
      int row = c >> 3, cis = (c & 7) ^ (row & 7);   // pre-swizzled source
      gld_lds16(kg + (size_t)(kt * 64 + row) * 64 + cis * 8,
                lK[buf] + (size_t)(p * 256 + wave * 64) * 8);
      gld_lds16(vg + (size_t)row * Nn + kt * 64 + cis * 8,
                lV[buf] + (size_t)(p * 256 + wave * 64) * 8);
    }
  };

  stage_tile(0, 0);
  __syncthreads();

  constexpr int NT = Nn / 64;
  for (int kt = 0; kt < NT; ++kt) {
    const int cur = kt & 1;
    if (kt + 1 < NT) stage_tile(kt + 1, cur ^ 1);  // DMA into idle buffer

    // S^T = K Q^T  (A=K rows kv, B=Q rows q) -> lane holds S[q=lane&15][k]
    f32x4 accT[4];
    __builtin_amdgcn_s_setprio(1);
#pragma unroll
    for (int nf = 0; nf < 4; ++nf) {
      int row = nf * 16 + (lane & 15);
      bf16x8 kF0 = *(const bf16x8*)(lK[cur] + ((row * 64 + 0 * 32 + g * 8) ^ ((row & 7) << 3)));
      bf16x8 kF1 = *(const bf16x8*)(lK[cur] + ((row * 64 + 1 * 32 + g * 8) ^ ((row & 7) << 3)));
      f32x4 sacc = {};
      sacc = __builtin_amdgcn_mfma_f32_16x16x32_bf16(kF0, qF[0], sacc, 0, 0, 0);
      sacc = __builtin_amdgcn_mfma_f32_16x16x32_bf16(kF1, qF[1], sacc, 0, 0, 0);
      accT[nf] = sacc;
    }
    __builtin_amdgcn_s_setprio(0);

    // P = exp2(S^T): lane-local row sums; packed b64 writes to pbuf[q][k]
    {
      int prow = lane & 15;
      float ps = 0.f;
#pragma unroll
      for (int nf = 0; nf < 4; ++nf) {
        bf16x4 pk;
#pragma unroll
        for (int r = 0; r < 4; ++r) {
          float pv = fexp2(accT[nf][r]);
          ps += pv;
          pk[r] = (__bf16)pv;
        }
        int idx = (prow * 64 + nf * 16 + g * 4) ^ ((prow & 7) << 3);
        *(bf16x4*)(pbuf[wave] + idx) = pk;
      }
      LsL += ps;
    }

    // O += P V  (A=P from pbuf, B=V^T from lV)
    __builtin_amdgcn_s_setprio(1);
#pragma unroll
    for (int kd = 0; kd < 2; ++kd) {
      int prow = lane & 15;
      bf16x8 pF = *(const bf16x8*)(pbuf[wave] + ((prow * 64 + kd * 32 + g * 8) ^ ((prow & 7) << 3)));
#pragma unroll
      for (int nf = 0; nf < 4; ++nf) {
        int row = nf * 16 + (lane & 15);
        bf16x8 vF = *(const bf16x8*)(lV[cur] + ((row * 64 + kd * 32 + g * 8) ^ ((row & 7) << 3)));
        accO[nf] = __builtin_amdgcn_mfma_f32_16x16x32_bf16(pF, vF, accO[nf], 0, 0, 0);
      }
    }
    __builtin_amdgcn_s_setprio(0);

    __syncthreads();                   // drains DMA; next buffer ready
  }

  // reduce row sums across the 4 lane-groups; redistribute per accO row
  float s = LsL;
  s += __shfl_xor(s, 16);
  s += __shfl_xor(s, 32);
  // lane holds total for q = lane&15

  const int b = bh >> 4, h = bh & 15;
#pragma unroll
  for (int r = 0; r < 4; ++r) {
    float inv = 1.0f / __shfl(s, g * 4 + r);   // Ls[q = g*4+r]
    int qrow = q0 + g * 4 + r;
#pragma unroll
    for (int nf = 0; nf < 4; ++nf) {
      int d = nf * 16 + (lane & 15);
      attn_o[((size_t)(b * Nn + qrow)) * Cc + h * 64 + d] = f2bf(accO[nf][r] * inv);
    }
  }
}

// ---------------------------------------------------------------------------
extern "C" void kernel_launch(void* const* d_in, const int* in_sizes, int n_in,
                              void* d_out, int out_size, void* d_ws, size_t ws_size,
                              hipStream_t stream) {
  (void)in_sizes; (void)n_in; (void)out_size; (void)ws_size;
  const float* x  = (const float*)d_in[0];
  const float* wq = (const float*)d_in[1];
  const float* wk = (const float*)d_in[2];
  const float* wv = (const float*)d_in[3];
  const float* wp = (const float*)d_in[4];
  const float* bp = (const float*)d_in[5];
  const float* cw = (const float*)d_in[6];
  const float* sw = (const float*)d_in[7];
  float* out = (float*)d_out;

  const size_t M1 = 1u << 20;           // 1M elems
  bf16* x_bf  = (bf16*)d_ws;            // 4M  (reused as ao_ws after qkv)
  bf16* wq_bf = x_bf + 4 * M1;          // 1M
  bf16* wk_bf = wq_bf + M1;             // 1M
  bf16* wv_bf = wk_bf + M1;             // 1M
  bf16* wp_bf = wv_bf + M1;             // 1M
  bf16* q_ws  = wp_bf + M1;             // 4M
  bf16* k_ws  = q_ws + 4 * M1;          // 4M
  bf16* vt_ws = k_ws + 4 * M1;          // 4M  -> total 20M elems = 40 MB
  bf16* ao_ws = x_bf;                   // overlay: x_bf dead after k_qkv

  k_cvt  <<<dim3(4096),    dim3(256), 0, stream>>>(x, wq, wk, wv, wp,
                                                   x_bf, wq_bf, wk_bf, wv_bf, wp_bf);
  k_qkv  <<<dim3(768),     dim3(256), 0, stream>>>(x_bf, wq_bf, wk_bf, wv_bf,
                                                   q_ws, k_ws, vt_ws, cw, sw);
  k_flash<<<dim3(1024),    dim3(256), 0, stream>>>(q_ws, k_ws, vt_ws, ao_ws);
  k_proj <<<dim3(64, 8),   dim3(256), 0, stream>>>(ao_ws, wp_bf, out, bp);
}

// Round 16
// 121.102 us; speedup vs baseline: 1.0583x; 1.0583x over previous
//
#include <hip/hip_runtime.h>
#include <hip/hip_bf16.h>
#include <stdint.h>

#define DEVI __device__ __forceinline__

using bf16 = __hip_bfloat16;
typedef __bf16 bf16x8 __attribute__((ext_vector_type(8)));
typedef __bf16 bf16x4 __attribute__((ext_vector_type(4)));
typedef float f32x4 __attribute__((ext_vector_type(4)));

static constexpr int Bb = 2, Nn = 2048, Cc = 1024, Hh = 16, Dd = 64;
static constexpr float CSC = 0.125f * 1.44269504088896340736f;  // scale*log2(e)

DEVI bf16 f2bf(float x) { __bf16 h = (__bf16)x; return *(bf16*)&h; }
DEVI float fexp2(float x) { return __builtin_amdgcn_exp2f(x); }

DEVI bf16x8 cvt8(f32x4 a, f32x4 b) {
  bf16x8 r;
  r[0] = (__bf16)a[0]; r[1] = (__bf16)a[1]; r[2] = (__bf16)a[2]; r[3] = (__bf16)a[3];
  r[4] = (__bf16)b[0]; r[5] = (__bf16)b[1]; r[6] = (__bf16)b[2]; r[7] = (__bf16)b[3];
  return r;
}

// async global->LDS, 16B/lane; LDS dest = wave-uniform base + lane*16
DEVI void gld_lds16(const bf16* g, bf16* l) {
  __builtin_amdgcn_global_load_lds(
      (__attribute__((address_space(1))) void*)(g),
      (__attribute__((address_space(3))) void*)(l),
      16, 0, 0);
}

// ---------------------------------------------------------------------------
// f32 -> bf16 pre-convert: x(2048 blks) + wq/wk/wv/wp(512 blks each) = 4096.
// ---------------------------------------------------------------------------
__global__ __launch_bounds__(256) void k_cvt(const float* __restrict__ x,
                                             const float* __restrict__ wq,
                                             const float* __restrict__ wk,
                                             const float* __restrict__ wv,
                                             const float* __restrict__ wp,
                                             bf16* xb, bf16* wqb, bf16* wkb,
                                             bf16* wvb, bf16* wpb) {
  int bid = blockIdx.x;
  const float* src; bf16* dst; size_t off;
  if (bid < 2048) {
    src = x; dst = xb; off = (size_t)bid * 2048;
  } else {
    int s = (bid - 2048) >> 9, r = (bid - 2048) & 511;
    off = (size_t)r * 2048;
    src = s == 0 ? wq : s == 1 ? wk : s == 2 ? wv : wp;
    dst = s == 0 ? wqb : s == 1 ? wkb : s == 2 ? wvb : wpb;
  }
  size_t i = off + (size_t)threadIdx.x * 8;
  f32x4 a = *(const f32x4*)(src + i);
  f32x4 b = *(const f32x4*)(src + i + 4);
  *(bf16x8*)(dst + i) = cvt8(a, b);
}

// ---------------------------------------------------------------------------
// bf16 GEMM, global_load_lds staging, m97 2-barrier structure (r8-proven).
// out[m][n] = sum_k A[m][k]*B[n][k]; BM=MFC*32, BN=128, BK=32; 256 thr.
// ---------------------------------------------------------------------------
template <int MFC, class Epi>
DEVI void gemm_lds_body(const bf16* __restrict__ A, const bf16* __restrict__ Bw,
                        int K, int m0, int n0, bf16* lA, bf16* lB, Epi epi) {
  constexpr int BM = MFC * 32;
  constexpr int PA = BM / 64;          // A 16B-chunks per thread
  const int t = threadIdx.x;
  const int lane = t & 63, wave = t >> 6;
  const int wr = wave >> 1, wc = wave & 1;

  f32x4 acc[MFC][4] = {};

  for (int k0 = 0; k0 < K; k0 += 32) {
    __syncthreads();                   // prev compute done, LDS free
#pragma unroll
    for (int p = 0; p < PA; ++p) {
      int c = p * 256 + t;
      int row = c >> 2, col = (c & 3) * 8;
      gld_lds16(A + (size_t)(m0 + row) * K + k0 + col,
                lA + (size_t)(p * 256 + wave * 64) * 8);
    }
#pragma unroll
    for (int p = 0; p < 2; ++p) {
      int c = p * 256 + t;
      int row = c >> 2, col = (c & 3) * 8;
      gld_lds16(Bw + (size_t)(n0 + row) * K + k0 + col,
                lB + (size_t)(p * 256 + wave * 64) * 8);
    }
    __syncthreads();                   // drains vmcnt -> tile ready

    bf16x8 aF[MFC];
#pragma unroll
    for (int mf = 0; mf < MFC; ++mf)
      aF[mf] = *(const bf16x8*)(lA + (wr * (BM / 2) + mf * 16 + (lane & 15)) * 32 + (lane >> 4) * 8);
#pragma unroll
    for (int nf = 0; nf < 4; ++nf) {
      bf16x8 bF = *(const bf16x8*)(lB + (wc * 64 + nf * 16 + (lane & 15)) * 32 + (lane >> 4) * 8);
#pragma unroll
      for (int mf = 0; mf < MFC; ++mf)
        acc[mf][nf] = __builtin_amdgcn_mfma_f32_16x16x32_bf16(aF[mf], bF, acc[mf][nf], 0, 0, 0);
    }
  }

#pragma unroll
  for (int mf = 0; mf < MFC; ++mf)
#pragma unroll
    for (int nf = 0; nf < 4; ++nf)
#pragma unroll
      for (int r = 0; r < 4; ++r) {
        int gm = m0 + wr * (BM / 2) + mf * 16 + (lane >> 4) * 4 + r;
        int gn = n0 + wc * 64 + nf * 16 + (lane & 15);
        epi(gm, gn, acc[mf][nf][r]);
      }
}

// Epilogues -----------------------------------------------------------------
struct EpiRope {  // rows=(b,n), cols=(h,d); RoPE (+opt scale) -> bf16 (b,h,n,d)
  bf16* dst; const float* cosw; const float* sinw; float scale;
  DEVI void operator()(int gm, int gn, float v) const {
    int b = gm >> 11, n = gm & 2047;
    int h = gn >> 6, d = gn & 63;
    int i = d >> 1;
    float c = cosw[n * 32 + i], s = sinw[n * 32 + i];
    float p = __shfl_xor(v, 1);
    float o = (d & 1) ? (p * s + v * c) : (v * c - p * s);
    dst[((size_t)(b * Hh + h) * Nn + n) * 64 + d] = f2bf(o * scale);
  }
};

struct EpiVt {  // rows=c=(h,d), cols=(b,n); -> bf16 (b,h,d,n)
  bf16* dst;
  DEVI void operator()(int gm, int gn, float v) const {
    int h = gm >> 6, d = gm & 63;
    int b = gn >> 11, n = gn & 2047;
    dst[((size_t)(b * Hh + h) * 64 + d) * Nn + n] = f2bf(v);
  }
};

struct EpiProj {  // rows=(b,n), cols=c; +bias -> f32 row-major
  float* dst; const float* bias;
  DEVI void operator()(int gm, int gn, float v) const {
    dst[(size_t)gm * Cc + gn] = v + bias[gn];
  }
};

// Fused QKV: 768 blocks, XCD-clustered by x-panel: bid%8 == x_panel%8, so all
// consumers of one 128-row x panel (q,k GEMM rows; vt GEMM cols) share an L2.
__global__ __launch_bounds__(256) void k_qkv(const bf16* __restrict__ xb,
                                             const bf16* __restrict__ wqb,
                                             const bf16* __restrict__ wkb,
                                             const bf16* __restrict__ wvb,
                                             bf16* q_ws, bf16* k_ws, bf16* vt_ws,
                                             const float* __restrict__ cw,
                                             const float* __restrict__ sw) {
  __shared__ __align__(16) bf16 smem[256 * 32];
  bf16* lA = smem;
  bf16* lB = smem + 128 * 32;
  int bid = blockIdx.x;
  if (bid < 512) {
    int sub = bid & 255;
    int c = sub & 7, rest = sub >> 3;
    int m0 = (c + 8 * (rest & 3)) * 128;   // x panel (m%8 == bid%8)
    int n0 = (rest >> 2) * 128;
    bool isq = bid < 256;
    gemm_lds_body<4>(xb, isq ? wqb : wkb, Cc, m0, n0, lA, lB,
                     EpiRope{isq ? q_ws : k_ws, cw, sw, isq ? CSC : 1.0f});
  } else {
    int sub = bid - 512;
    int c = sub & 7, rest = sub >> 3;
    int n0 = (c + 8 * (rest & 3)) * 128;   // x panel (n%8 == bid%8)
    int m0 = (rest >> 2) * 128;            // wv rows
    gemm_lds_body<4>(wvb, xb, Cc, m0, n0, lA, lB, EpiVt{vt_ws});
  }
}

// Proj: BM=64 -> grid (64,8); wgid%8 == m-panel%8 already (x-fastest linear).
__global__ __launch_bounds__(256) void k_proj(const bf16* __restrict__ A,
                                              const bf16* __restrict__ W,
                                              float* dst, const float* __restrict__ bias) {
  __shared__ __align__(16) bf16 smem[192 * 32];
  gemm_lds_body<2>(A, W, Cc, blockIdx.x * 64, blockIdx.y * 128,
                   smem, smem + 64 * 32, EpiProj{dst, bias});
}

// ---------------------------------------------------------------------------
// Flash (r14 per-wave structure, halved staging): 256 blocks x 512 thr
// (8 waves); wave owns 32 q rows (2 subtiles); block q-tile 256.
// Swapped QK^T (acc=S^T) -> P rows lane-local -> pbuf[q][k] packed b64
// writes; nf-split Ls accumulators (break serial add chain). DMA staging
// (pre-swizzled source) into double-buffered lK/lV. No max tracking.
// XCD map: bid%8 = xcd; 4 bh per XCD -> K/V L2-resident.
// ---------------------------------------------------------------------------
__global__ __launch_bounds__(512) void k_flash(const bf16* __restrict__ q_ws,
                                               const bf16* __restrict__ k_ws,
                                               const bf16* __restrict__ vt_ws,
                                               bf16* __restrict__ attn_o) {
  __shared__ __align__(16) bf16 lK[2][64 * 64];
  __shared__ __align__(16) bf16 lV[2][64 * 64];
  __shared__ __align__(16) bf16 pbuf[8][32 * 64];

  const int t = threadIdx.x, lane = t & 63, wave = t >> 6;
  const int g = lane >> 4;
  const int bid = blockIdx.x;
  const int slot = bid >> 3;                    // [0,32) per XCD class
  const int bh = (bid & 7) * 4 + (slot >> 3);   // 4 bh per XCD
  const int q0 = (slot & 7) * 256 + wave * 32;  // 256 q-rows per block
  const bf16* qg = q_ws + (size_t)bh * Nn * 64;
  const bf16* kg = k_ws + (size_t)bh * Nn * 64;
  const bf16* vg = vt_ws + (size_t)bh * 64 * Nn;

  bf16x8 qF[2][2];
#pragma unroll
  for (int qs = 0; qs < 2; ++qs)
#pragma unroll
    for (int kd = 0; kd < 2; ++kd)
      qF[qs][kd] = *(const bf16x8*)(qg + (size_t)(q0 + qs * 16 + (lane & 15)) * 64 + kd * 32 + g * 8);

  f32x4 accO[2][4] = {};
  float LsV[2][4] = {};                 // nf-split partial sums (q = lane&15)

  // 512 threads stage 64 rows x 8 chunks (one 16B chunk per thread)
  auto stage_tile = [&](int kt, int buf) {
    int row = t >> 3, cis = (t & 7) ^ (row & 7);   // pre-swizzled source
    gld_lds16(kg + (size_t)(kt * 64 + row) * 64 + cis * 8,
              lK[buf] + (size_t)(wave * 64) * 8);
    gld_lds16(vg + (size_t)row * Nn + kt * 64 + cis * 8,
              lV[buf] + (size_t)(wave * 64) * 8);
  };

  stage_tile(0, 0);
  __syncthreads();

  constexpr int NT = Nn / 64;
  for (int kt = 0; kt < NT; ++kt) {
    const int cur = kt & 1;
    if (kt + 1 < NT) stage_tile(kt + 1, cur ^ 1);  // DMA into idle buffer

    // S^T = K Q^T  (A=K rows kv, B=Q rows q) -> lane holds S[q=lane&15][k]
    f32x4 accT[2][4];
    __builtin_amdgcn_s_setprio(1);
#pragma unroll
    for (int nf = 0; nf < 4; ++nf) {
      int row = nf * 16 + (lane & 15);
      bf16x8 kF0 = *(const bf16x8*)(lK[cur] + ((row * 64 + 0 * 32 + g * 8) ^ ((row & 7) << 3)));
      bf16x8 kF1 = *(const bf16x8*)(lK[cur] + ((row * 64 + 1 * 32 + g * 8) ^ ((row & 7) << 3)));
#pragma unroll
      for (int qs = 0; qs < 2; ++qs) {
        f32x4 sacc = {};
        sacc = __builtin_amdgcn_mfma_f32_16x16x32_bf16(kF0, qF[qs][0], sacc, 0, 0, 0);
        sacc = __builtin_amdgcn_mfma_f32_16x16x32_bf16(kF1, qF[qs][1], sacc, 0, 0, 0);
        accT[qs][nf] = sacc;
      }
    }
    __builtin_amdgcn_s_setprio(0);

    // P = exp2(S^T): nf-split lane-local sums; packed b64 writes to pbuf[q][k]
#pragma unroll
    for (int qs = 0; qs < 2; ++qs) {
      int prow = qs * 16 + (lane & 15);
#pragma unroll
      for (int nf = 0; nf < 4; ++nf) {
        bf16x4 pk;
        float ps = 0.f;
#pragma unroll
        for (int r = 0; r < 4; ++r) {
          float pv = fexp2(accT[qs][nf][r]);
          ps += pv;
          pk[r] = (__bf16)pv;
        }
        LsV[qs][nf] += ps;             // 4 independent chains per qs
        int idx = (prow * 64 + nf * 16 + g * 4) ^ ((prow & 7) << 3);
        *(bf16x4*)(pbuf[wave] + idx) = pk;
      }
    }

    // O += P V  (A=P from pbuf, B=V^T from lV)
    __builtin_amdgcn_s_setprio(1);
#pragma unroll
    for (int kd = 0; kd < 2; ++kd) {
      bf16x8 pF[2];
#pragma unroll
      for (int qs = 0; qs < 2; ++qs) {
        int prow = qs * 16 + (lane & 15);
        pF[qs] = *(const bf16x8*)(pbuf[wave] + ((prow * 64 + kd * 32 + g * 8) ^ ((prow & 7) << 3)));
      }
#pragma unroll
      for (int nf = 0; nf < 4; ++nf) {
        int row = nf * 16 + (lane & 15);
        bf16x8 vF = *(const bf16x8*)(lV[cur] + ((row * 64 + kd * 32 + g * 8) ^ ((row & 7) << 3)));
#pragma unroll
        for (int qs = 0; qs < 2; ++qs)
          accO[qs][nf] = __builtin_amdgcn_mfma_f32_16x16x32_bf16(pF[qs], vF, accO[qs][nf], 0, 0, 0);
      }
    }
    __builtin_amdgcn_s_setprio(0);

    __syncthreads();                   // drains DMA; next buffer ready
  }

  // combine nf-split sums, reduce across lane-groups, redistribute
  float Lq[2];
#pragma unroll
  for (int qs = 0; qs < 2; ++qs) {
    float s = (LsV[qs][0] + LsV[qs][1]) + (LsV[qs][2] + LsV[qs][3]);
    s += __shfl_xor(s, 16);
    s += __shfl_xor(s, 32);
    Lq[qs] = s;                        // lane holds total for q = qs*16+(lane&15)
  }

  const int b = bh >> 4, h = bh & 15;
#pragma unroll
  for (int qs = 0; qs < 2; ++qs)
#pragma unroll
    for (int r = 0; r < 4; ++r) {
      float inv = 1.0f / __shfl(Lq[qs], g * 4 + r);   // Ls[q = qs*16+g*4+r]
      int qrow = q0 + qs * 16 + g * 4 + r;
#pragma unroll
      for (int nf = 0; nf < 4; ++nf) {
        int d = nf * 16 + (lane & 15);
        attn_o[((size_t)(b * Nn + qrow)) * Cc + h * 64 + d] = f2bf(accO[qs][nf][r] * inv);
      }
    }
}

// ---------------------------------------------------------------------------
extern "C" void kernel_launch(void* const* d_in, const int* in_sizes, int n_in,
                              void* d_out, int out_size, void* d_ws, size_t ws_size,
                              hipStream_t stream) {
  (void)in_sizes; (void)n_in; (void)out_size; (void)ws_size;
  const float* x  = (const float*)d_in[0];
  const float* wq = (const float*)d_in[1];
  const float* wk = (const float*)d_in[2];
  const float* wv = (const float*)d_in[3];
  const float* wp = (const float*)d_in[4];
  const float* bp = (const float*)d_in[5];
  const float* cw = (const float*)d_in[6];
  const float* sw = (const float*)d_in[7];
  float* out = (float*)d_out;

  const size_t M1 = 1u << 20;           // 1M elems
  bf16* x_bf  = (bf16*)d_ws;            // 4M  (reused as ao_ws after qkv)
  bf16* wq_bf = x_bf + 4 * M1;          // 1M
  bf16* wk_bf = wq_bf + M1;             // 1M
  bf16* wv_bf = wk_bf + M1;             // 1M
  bf16* wp_bf = wv_bf + M1;             // 1M
  bf16* q_ws  = wp_bf + M1;             // 4M
  bf16* k_ws  = q_ws + 4 * M1;          // 4M
  bf16* vt_ws = k_ws + 4 * M1;          // 4M  -> total 20M elems = 40 MB
  bf16* ao_ws = x_bf;                   // overlay: x_bf dead after k_qkv

  k_cvt  <<<dim3(4096),    dim3(256), 0, stream>>>(x, wq, wk, wv, wp,
                                                   x_bf, wq_bf, wk_bf, wv_bf, wp_bf);
  k_qkv  <<<dim3(768),     dim3(256), 0, stream>>>(x_bf, wq_bf, wk_bf, wv_bf,
                                                   q_ws, k_ws, vt_ws, cw, sw);
  k_flash<<<dim3(256),     dim3(512), 0, stream>>>(q_ws, k_ws, vt_ws, ao_ws);
  k_proj <<<dim3(64, 8),   dim3(256), 0, stream>>>(ao_ws, wp_bf, out, bp);
}